// Round 15
// baseline (951.610 us; speedup 1.0000x reference)
//
#include <hip/hip_runtime.h>
#include <math.h>

// Problem constants (reference: S,B,I,H = 1024,512,5,32; G=4H=128)
#define S_LEN 1024
#define BATCH 512
#define HID   32

#define LOG2E 1.44269504088896340736f

__device__ __forceinline__ float fast_rcp(float x) { return __builtin_amdgcn_rcpf(x); }
__device__ __forceinline__ float fast_exp2(float x) { return __builtin_amdgcn_exp2f(x); }

// gfx950 v_permlane32_swap_b32 with vdst = vsrc = v:
//   r[0] = value the HIGH half held, r[1] = value the LOW half held
typedef unsigned int uint2v __attribute__((ext_vector_type(2)));
__device__ __forceinline__ void swap_halves(float v, float& hiAll, float& loAll) {
    uint2v r = __builtin_amdgcn_permlane32_swap(__float_as_uint(v),
                                                __float_as_uint(v),
                                                false, false);
    hiAll = __uint_as_float(r[0]);
    loAll = __uint_as_float(r[1]);
}

// Broadcast lane k's value (k constant after unroll) -> SGPR operand.
__device__ __forceinline__ float bcast(float v, int k) {
    return __int_as_float(__builtin_amdgcn_readlane(__float_as_int(v), k));
}

// Full-wave (64-lane) sum via DPP — VALU-only (round-11: -118 us vs shfl).
// Valid total lands in LANE 63.
__device__ __forceinline__ float wave_sum64_dpp(float v) {
    float s = v;
    s += __int_as_float(__builtin_amdgcn_update_dpp(
             0, __float_as_int(s), 0x111, 0xf, 0xf, true));   // row_shr:1
    s += __int_as_float(__builtin_amdgcn_update_dpp(
             0, __float_as_int(s), 0x112, 0xf, 0xf, true));   // row_shr:2
    s += __int_as_float(__builtin_amdgcn_update_dpp(
             0, __float_as_int(s), 0x114, 0xf, 0xf, true));   // row_shr:4
    s += __int_as_float(__builtin_amdgcn_update_dpp(
             0, __float_as_int(s), 0x118, 0xf, 0xf, true));   // row_shr:8
    s += __int_as_float(__builtin_amdgcn_update_dpp(
             0, __float_as_int(s), 0x142, 0xa, 0xf, true));   // row_bcast:15
    s += __int_as_float(__builtin_amdgcn_update_dpp(
             0, __float_as_int(s), 0x143, 0xc, 0xf, true));   // row_bcast:31
    return s;
}

// Load one 32-float weight row into registers, pre-scaled.
#define LOADROW(dst, base, row, sc)                                            \
    {                                                                          \
        const float4* W_ = reinterpret_cast<const float4*>((base) +            \
                                                    (size_t)(row) * HID);      \
        _Pragma("unroll")                                                      \
        for (int k4 = 0; k4 < 8; ++k4) {                                       \
            float4 v_ = W_[k4];                                                \
            dst[4 * k4 + 0] = v_.x * (sc);                                     \
            dst[4 * k4 + 1] = v_.y * (sc);                                     \
            dst[4 * k4 + 2] = v_.z * (sc);                                     \
            dst[4 * k4 + 3] = v_.w * (sc);                                     \
        }                                                                      \
    }

// Fused 3-layer LSTM + collapsed MLP head — ASYNC PRODUCER-CONSUMER pipeline.
// Block = 192 threads = 3 waves; wave w = layer w; blockIdx = batch element;
// 512 blocks = 2 blocks/CU co-resident.
//
// ZERO BARRIERS IN THE LOOP (this round's change). The dependency graph is a
// 2-edge chain (wave0 -> wave1 -> wave2), not all-to-all; the block-wide
// s_barrier of rounds 0-14 charged every tick-pair with max(3 waves' arrival)
// — coupling that survived every barrier-COUNT change (R10/R13 A/Bs). Here
// each wave free-runs: producer publishes a sequence counter prog[w]=s+1
// AFTER writing h(s) into a depth-8 LDS ring (DS ops are in-order per wave,
// so counter-visible => data-visible); consumer spin-checks prog (value
// PREFETCHED one tick early -> steady-state check costs ~2 VALU, no exposed
// ds latency) and publishes cons for ring backpressure (producer needs
// cons >= s-7 before overwriting slot s&7).
// Lag-0 true dataflow: wave w at step s consumes h_{w-1}(s) -> no pipeline
// skew, no active-guards, branchless 1024-tick loop.
//
// MLP COLLAPSE: y = relu(v.h2 + cbias), v = 0.5*W1^T(W2^T w3); VALU-only DPP
// reduce; store from lane 63, never waited (no vmcnt drain anywhere).
// Lane l owns rows gA=l, gB=l+64 (torch order i,f,g,o); pre-scaled by log2e
// (g rows by 2*log2e): activation is uniform sigma(y)=rcp(1+exp2(-y));
// tanh(g)=2*sigma(2g)-1. x block-slice staged in LDS once.
// waves_per_eu(2) pins regs under the 256 combined cliff (round-9 lesson).
__global__ __launch_bounds__(192)
__attribute__((amdgpu_waves_per_eu(2)))
void lstm3_async(const float* __restrict__ x,
                 const float* __restrict__ Wih0, const float* __restrict__ Whh0,
                 const float* __restrict__ bih0, const float* __restrict__ bhh0,
                 const float* __restrict__ Wih1, const float* __restrict__ Whh1,
                 const float* __restrict__ bih1, const float* __restrict__ bhh1,
                 const float* __restrict__ Wih2, const float* __restrict__ Whh2,
                 const float* __restrict__ bih2, const float* __restrict__ bhh2,
                 const float* __restrict__ w1, const float* __restrict__ b1,
                 const float* __restrict__ w2, const float* __restrict__ b2,
                 const float* __restrict__ w3, const float* __restrict__ b3,
                 float* __restrict__ out)
{
    const int b = blockIdx.x;
    const int w = threadIdx.x >> 6;   // wave id == layer id, 0..2
    const int l = threadIdx.x & 63;
    const int j = l & 31;
    const int gA = l;
    const int gB = l + 64;
    const float sA = LOG2E;
    const float sB = (l < 32) ? (2.0f * LOG2E) : LOG2E;  // g rows get 2*log2e

    // x slice: xl4[s] = x[s][b][0..3], xl1[s] = x[s][b][4]
    __shared__ float4 xl4[S_LEN];     // 16 KB
    __shared__ float  xl1[S_LEN];     //  4 KB
    // ring[slot][src_wave][unit]; slot = s & 7 (depth-8). 2 KB.
    __shared__ float ring[8][2][HID];
    // sync counters: [0..1]=prog (ticks produced by wave 0/1),
    //                [4..5]=cons (ticks consumed FROM wave 0/1). Spread out.
    __shared__ int syncv[8];
    volatile int* const vs = (volatile int*)syncv;

    if (threadIdx.x < 8) syncv[threadIdx.x] = 0;
    {
        float* xf = reinterpret_cast<float*>(xl4);
        for (int idx = threadIdx.x; idx < S_LEN * 5; idx += 192) {
            const int s = idx / 5;
            const int c = idx - 5 * s;
            const float v = x[(size_t)s * (BATCH * 5) + b * 5 + c];
            if (c < 4) xf[s * 4 + c] = v;
            else       xl1[s] = v;
        }
    }

    const float* Wih = (w == 0) ? Wih0 : (w == 1) ? Wih1 : Wih2;
    const float* Whh = (w == 0) ? Whh0 : (w == 1) ? Whh1 : Whh2;
    const float* bih = (w == 0) ? bih0 : (w == 1) ? bih1 : bih2;
    const float* bhh = (w == 0) ? bhh0 : (w == 1) ? bhh1 : bhh2;

    // Recurrent weight rows in registers (all waves), pre-scaled
    float whA[HID], whB[HID];
    LOADROW(whA, Whh, gA, sA);
    LOADROW(whB, Whh, gB, sB);
    // Input weight rows: wave 0 has KIN=5, waves 1/2 have KIN=32.
    float wiA[HID], wiB[HID];
    float wxA[5], wxB[5];
    if (w == 0) {
#pragma unroll
        for (int k = 0; k < 5; ++k) {
            wxA[k] = Wih[gA * 5 + k] * sA;
            wxB[k] = Wih[gB * 5 + k] * sB;
        }
    } else {
        LOADROW(wiA, Wih, gA, sA);
        LOADROW(wiB, Wih, gB, sB);
    }
    const float biasA = (bih[gA] + bhh[gA]) * sA;
    const float biasB = (bih[gB] + bhh[gB]) * sB;

    // Collapsed MLP: v_j (x0.5 for the 64-lane DPP sum) and cbias (wave 2)
    float v_j = 0.0f, cbias = 0.0f;
    if (w == 2) {
        float uacc[HID];
#pragma unroll
        for (int k = 0; k < HID; ++k) uacc[k] = 0.0f;
        for (int r = 0; r < HID; ++r) {         // u = w3^T W2 (uniform loads)
            const float w3r = w3[r];
#pragma unroll
            for (int k = 0; k < HID; ++k)
                uacc[k] += w3r * w2[r * HID + k];
        }
#pragma unroll
        for (int k = 0; k < HID; ++k) {
            v_j   += uacc[k] * w1[k * HID + j];
            cbias += uacc[k] * b1[k];
        }
        for (int r = 0; r < HID; ++r) cbias += w3[r] * b2[r];
        cbias += b3[0];
        v_j *= 0.5f;    // halves replicated -> 64-lane sum double-counts
    }

    float c = 0.0f;
    float h_own = 0.0f;   // own-layer h(s-1), unit j, identical in both halves

    __syncthreads();  // one-time: staging + counter init visible

    int Ppref = 0;    // prefetched prog[w-1] (w>0)
    int Cpref = 0;    // prefetched cons[w]   (w<2)

#pragma unroll 1
    for (int s = 0; s < S_LEN; ++s) {
        const int slot = s & 7;

        // ---- acquire: input h_{w-1}(s) published? (steady state: Ppref
        //      already >= s+1 from last tick's prefetch -> 2 VALU, no wait)
        if (w > 0 && Ppref < s + 1) {
            int p;
            do { p = vs[w - 1]; } while (p < s + 1);
            Ppref = p;
        }
        // ---- backpressure: consumer must have read slot's old tick s-8
        if (w < 2 && Cpref < s - 7) {
            int q;
            do { q = vs[4 + w]; } while (q < s - 7);
            Cpref = q;
        }
        asm volatile("" ::: "memory");   // no data op hoisted above acquire

        // refresh prefetches NOW — latency hides under this tick's matvecs
        if (w > 0) Ppref = vs[w - 1];
        if (w < 2) Cpref = vs[4 + w];

        // ---- gate matvecs: acc = bias + Whh*h_own + Wih*input ----
        float aA0 = biasA, aA1 = 0.f, aA2 = 0.f, aA3 = 0.f;
        float aB0 = biasB, aB1 = 0.f, aB2 = 0.f, aB3 = 0.f;

        // own h via readlane broadcast (register-only, no LDS)
#pragma unroll
        for (int k4 = 0; k4 < HID / 4; ++k4) {
            const float h0 = bcast(h_own, 4 * k4 + 0);
            const float h1 = bcast(h_own, 4 * k4 + 1);
            const float h2 = bcast(h_own, 4 * k4 + 2);
            const float h3 = bcast(h_own, 4 * k4 + 3);
            aA0 += whA[4 * k4 + 0] * h0;
            aA1 += whA[4 * k4 + 1] * h1;
            aA2 += whA[4 * k4 + 2] * h2;
            aA3 += whA[4 * k4 + 3] * h3;
            aB0 += whB[4 * k4 + 0] * h0;
            aB1 += whB[4 * k4 + 1] * h1;
            aB2 += whB[4 * k4 + 2] * h2;
            aB3 += whB[4 * k4 + 3] * h3;
        }

        if (w == 0) {
            const float4 xv = xl4[s];
            const float  x4 = xl1[s];
            aA0 += wxA[0] * xv.x; aB0 += wxB[0] * xv.x;
            aA1 += wxA[1] * xv.y; aB1 += wxB[1] * xv.y;
            aA2 += wxA[2] * xv.z; aB2 += wxB[2] * xv.z;
            aA3 += wxA[3] * xv.w; aB3 += wxB[3] * xv.w;
            aA0 += wxA[4] * x4;   aB0 += wxB[4] * x4;
        } else {
            // input = h_{w-1}(s) from ring (broadcast b128 reads)
            const float4* hin4 =
                reinterpret_cast<const float4*>(&ring[slot][w - 1][0]);
#pragma unroll
            for (int k4 = 0; k4 < HID / 4; ++k4) {
                const float4 hv = hin4[k4];
                aA0 += wiA[4 * k4 + 0] * hv.x;
                aA1 += wiA[4 * k4 + 1] * hv.y;
                aA2 += wiA[4 * k4 + 2] * hv.z;
                aA3 += wiA[4 * k4 + 3] * hv.w;
                aB0 += wiB[4 * k4 + 0] * hv.x;
                aB1 += wiB[4 * k4 + 1] * hv.y;
                aB2 += wiB[4 * k4 + 2] * hv.z;
                aB3 += wiB[4 * k4 + 3] * hv.w;
            }
            // publish consumption: ring reads above are issued (DS in-order
            // per wave), so producer seeing cons=s+1 may safely overwrite.
            asm volatile("" ::: "memory");
            if (l == 0) vs[4 + (w - 1)] = s + 1;
        }
        const float accA = (aA0 + aA1) + (aA2 + aA3);
        const float accB = (aB0 + aB1) + (aB2 + aB3);

        // ---- half-exchange: all lanes get all 4 gates of unit j ----
        float yf, yi, yo, yg;
        swap_halves(accA, yf, yi);   // low half held i, high half held f
        swap_halves(accB, yo, yg);   // low half held g, high half held o

        const float gi = fast_rcp(1.0f + fast_exp2(-yi));
        const float gf = fast_rcp(1.0f + fast_exp2(-yf));
        const float sg = fast_rcp(1.0f + fast_exp2(-yg));
        const float go = fast_rcp(1.0f + fast_exp2(-yo));
        const float gg = 2.0f * sg - 1.0f;      // tanh(g) = 2*sigma(2g) - 1

        const float c_new = gf * c + gi * gg;
        const float e  = fast_exp2(-2.0f * LOG2E * fabsf(c_new));
        const float tc = copysignf((1.0f - e) * fast_rcp(1.0f + e), c_new);
        const float h = go * tc;                // identical in both halves

        c = c_new;
        h_own = h;
        if (w < 2) {
            if (l < 32) ring[slot][w][j] = h;   // data ...
            asm volatile("" ::: "memory");
            if (l == 0) vs[w] = s + 1;          // ... then counter (in-order)
        } else {
            // collapsed MLP: y = relu(v.h + cbias), VALU-only DPP reduce
            const float tot = wave_sum64_dpp(h * v_j);
            const float y = fmaxf(tot + cbias, 0.0f);
            if (l == 63)
                out[(size_t)s * BATCH + b] = y; // streamed, never waited
        }
    }
}

extern "C" void kernel_launch(void* const* d_in, const int* in_sizes, int n_in,
                              void* d_out, int out_size, void* d_ws, size_t ws_size,
                              hipStream_t stream)
{
    const float* x    = (const float*)d_in[0];
    const float* Wih0 = (const float*)d_in[1];
    const float* Whh0 = (const float*)d_in[2];
    const float* bih0 = (const float*)d_in[3];
    const float* bhh0 = (const float*)d_in[4];
    const float* Wih1 = (const float*)d_in[5];
    const float* Whh1 = (const float*)d_in[6];
    const float* bih1 = (const float*)d_in[7];
    const float* bhh1 = (const float*)d_in[8];
    const float* Wih2 = (const float*)d_in[9];
    const float* Whh2 = (const float*)d_in[10];
    const float* bih2 = (const float*)d_in[11];
    const float* bhh2 = (const float*)d_in[12];
    const float* w1   = (const float*)d_in[13];
    const float* b1   = (const float*)d_in[14];
    const float* w2   = (const float*)d_in[15];
    const float* b2   = (const float*)d_in[16];
    const float* w3   = (const float*)d_in[17];
    const float* b3   = (const float*)d_in[18];

    lstm3_async<<<BATCH, 192, 0, stream>>>(x, Wih0, Whh0, bih0, bhh0,
                                           Wih1, Whh1, bih1, bhh1,
                                           Wih2, Whh2, bih2, bhh2,
                                           w1, b1, w2, b2, w3, b3,
                                           (float*)d_out);
}

// Round 16
// 872.969 us; speedup vs baseline: 1.0901x; 1.0901x over previous
//
#include <hip/hip_runtime.h>
#include <math.h>

// Problem constants (reference: S,B,I,H = 1024,512,5,32; G=4H=128)
#define S_LEN 1024
#define BATCH 512
#define HID   32

#define LOG2E 1.44269504088896340736f

__device__ __forceinline__ float fast_rcp(float x) { return __builtin_amdgcn_rcpf(x); }
__device__ __forceinline__ float fast_exp2(float x) { return __builtin_amdgcn_exp2f(x); }

// Barrier WITHOUT vmcnt drain (out stores stream; never waited in-loop).
__device__ __forceinline__ void tick_barrier() {
    asm volatile("s_waitcnt lgkmcnt(0)" ::: "memory");
    __builtin_amdgcn_s_barrier();
    asm volatile("" ::: "memory");   // compiler fence: no LDS op hoisted above
}

// gfx950 v_permlane32_swap_b32 with vdst = vsrc = v:
//   r[0] = value the HIGH half held, r[1] = value the LOW half held
typedef unsigned int uint2v __attribute__((ext_vector_type(2)));
__device__ __forceinline__ void swap_halves(float v, float& hiAll, float& loAll) {
    uint2v r = __builtin_amdgcn_permlane32_swap(__float_as_uint(v),
                                                __float_as_uint(v),
                                                false, false);
    hiAll = __uint_as_float(r[0]);
    loAll = __uint_as_float(r[1]);
}

// Broadcast lane k's value (k constant after unroll) -> SGPR operand.
__device__ __forceinline__ float bcast(float v, int k) {
    return __int_as_float(__builtin_amdgcn_readlane(__float_as_int(v), k));
}

// Full-wave (64-lane) sum via DPP — VALU-only (round-11: -118 us vs shfl).
// Valid total lands in LANE 63.
__device__ __forceinline__ float wave_sum64_dpp(float v) {
    float s = v;
    s += __int_as_float(__builtin_amdgcn_update_dpp(
             0, __float_as_int(s), 0x111, 0xf, 0xf, true));   // row_shr:1
    s += __int_as_float(__builtin_amdgcn_update_dpp(
             0, __float_as_int(s), 0x112, 0xf, 0xf, true));   // row_shr:2
    s += __int_as_float(__builtin_amdgcn_update_dpp(
             0, __float_as_int(s), 0x114, 0xf, 0xf, true));   // row_shr:4
    s += __int_as_float(__builtin_amdgcn_update_dpp(
             0, __float_as_int(s), 0x118, 0xf, 0xf, true));   // row_shr:8
    s += __int_as_float(__builtin_amdgcn_update_dpp(
             0, __float_as_int(s), 0x142, 0xa, 0xf, true));   // row_bcast:15
    s += __int_as_float(__builtin_amdgcn_update_dpp(
             0, __float_as_int(s), 0x143, 0xc, 0xf, true));   // row_bcast:31
    return s;
}

// Load one 32-float weight row into registers, pre-scaled.
#define LOADROW(dst, base, row, sc)                                            \
    {                                                                          \
        const float4* W_ = reinterpret_cast<const float4*>((base) +            \
                                                    (size_t)(row) * HID);      \
        _Pragma("unroll")                                                      \
        for (int k4 = 0; k4 < 8; ++k4) {                                       \
            float4 v_ = W_[k4];                                                \
            dst[4 * k4 + 0] = v_.x * (sc);                                     \
            dst[4 * k4 + 1] = v_.y * (sc);                                     \
            dst[4 * k4 + 2] = v_.z * (sc);                                     \
            dst[4 * k4 + 3] = v_.w * (sc);                                     \
        }                                                                      \
    }

// Fused 3-layer LSTM + collapsed MLP head — round-11 configuration RESTORED
// (848 us total; proven optimum across 15 rounds: 6 structural rewrites and
// 8 micro/coupling variants all regressed or tied). Block = 192 threads =
// 3 waves; wave w = layer w; blockIdx = batch element; 512 blocks = 2
// blocks/CU co-resident (cross-block overlap hides per-wave stalls; t-loop
// unroll-1 + waves_per_eu(2) keep combined regs under the 256 cliff).
//
// LAG-2 PIPELINE: wave w processes s = t - 2w; ring depth 4 (writer t&3,
// reader (t&3)^2); ONE lgkmcnt-only barrier per tick-pair.
//
// MLP COLLAPSE: y = relu(v.h2 + cbias), v = 0.5*W1^T(W2^T w3); VALU-only DPP
// reduce; store from lane 63, never waited (no vmcnt drain anywhere).
//
// Tail micro-cuts (this round, on the serial dependent chain):
//   tanh(c) = 2*rcp(1+exp2(-2*log2e*c)) - 1  (no fabs/copysign; limits:
//   c->+inf => 1, c->-inf => -1), and c_new folded as gf*c + 2*(gi*sg) - gi.
// Lane l owns rows gA=l, gB=l+64 (torch order i,f,g,o); weights pre-scaled
// by log2e (g rows by 2*log2e): activation is uniform sigma(y) =
// rcp(1+exp2(-y)); tanh(g)=2*sigma(2g)-1. x block-slice staged in LDS once.
__global__ __launch_bounds__(192)
__attribute__((amdgpu_waves_per_eu(2)))
void lstm3_fused(const float* __restrict__ x,
                 const float* __restrict__ Wih0, const float* __restrict__ Whh0,
                 const float* __restrict__ bih0, const float* __restrict__ bhh0,
                 const float* __restrict__ Wih1, const float* __restrict__ Whh1,
                 const float* __restrict__ bih1, const float* __restrict__ bhh1,
                 const float* __restrict__ Wih2, const float* __restrict__ Whh2,
                 const float* __restrict__ bih2, const float* __restrict__ bhh2,
                 const float* __restrict__ w1, const float* __restrict__ b1,
                 const float* __restrict__ w2, const float* __restrict__ b2,
                 const float* __restrict__ w3, const float* __restrict__ b3,
                 float* __restrict__ out)
{
    const int b = blockIdx.x;
    const int w = threadIdx.x >> 6;   // wave id == layer id, 0..2
    const int l = threadIdx.x & 63;
    const int j = l & 31;
    const int gA = l;
    const int gB = l + 64;
    const float sA = LOG2E;
    const float sB = (l < 32) ? (2.0f * LOG2E) : LOG2E;  // g rows get 2*log2e

    // x slice: xl4[s] = x[s][b][0..3], xl1[s] = x[s][b][4]
    __shared__ float4 xl4[S_LEN];     // 16 KB
    __shared__ float  xl1[S_LEN];     //  4 KB
    // ring[slot][src_wave][unit]; slot = tick & 3 (lag-2, depth-4)
    __shared__ float ring[4][2][HID];

    for (int i = threadIdx.x; i < 4 * 2 * HID; i += 192)
        (&ring[0][0][0])[i] = 0.0f;
    {
        float* xf = reinterpret_cast<float*>(xl4);
        for (int idx = threadIdx.x; idx < S_LEN * 5; idx += 192) {
            const int s = idx / 5;
            const int c = idx - 5 * s;
            const float v = x[(size_t)s * (BATCH * 5) + b * 5 + c];
            if (c < 4) xf[s * 4 + c] = v;
            else       xl1[s] = v;
        }
    }

    const float* Wih = (w == 0) ? Wih0 : (w == 1) ? Wih1 : Wih2;
    const float* Whh = (w == 0) ? Whh0 : (w == 1) ? Whh1 : Whh2;
    const float* bih = (w == 0) ? bih0 : (w == 1) ? bih1 : bih2;
    const float* bhh = (w == 0) ? bhh0 : (w == 1) ? bhh1 : bhh2;

    // Recurrent weight rows in registers (all waves), pre-scaled
    float whA[HID], whB[HID];
    LOADROW(whA, Whh, gA, sA);
    LOADROW(whB, Whh, gB, sB);
    // Input weight rows: wave 0 has KIN=5, waves 1/2 have KIN=32.
    float wiA[HID], wiB[HID];
    float wxA[5], wxB[5];
    if (w == 0) {
#pragma unroll
        for (int k = 0; k < 5; ++k) {
            wxA[k] = Wih[gA * 5 + k] * sA;
            wxB[k] = Wih[gB * 5 + k] * sB;
        }
    } else {
        LOADROW(wiA, Wih, gA, sA);
        LOADROW(wiB, Wih, gB, sB);
    }
    const float biasA = (bih[gA] + bhh[gA]) * sA;
    const float biasB = (bih[gB] + bhh[gB]) * sB;

    // Collapsed MLP: v_j (x0.5 for the 64-lane DPP sum) and cbias (wave 2)
    float v_j = 0.0f, cbias = 0.0f;
    if (w == 2) {
        float uacc[HID];
#pragma unroll
        for (int k = 0; k < HID; ++k) uacc[k] = 0.0f;
        for (int r = 0; r < HID; ++r) {         // u = w3^T W2 (uniform loads)
            const float w3r = w3[r];
#pragma unroll
            for (int k = 0; k < HID; ++k)
                uacc[k] += w3r * w2[r * HID + k];
        }
#pragma unroll
        for (int k = 0; k < HID; ++k) {
            v_j   += uacc[k] * w1[k * HID + j];
            cbias += uacc[k] * b1[k];
        }
        for (int r = 0; r < HID; ++r) cbias += w3[r] * b2[r];
        cbias += b3[0];
        v_j *= 0.5f;    // halves replicated -> 64-lane sum double-counts
    }

    float c = 0.0f;
    float h_own = 0.0f;   // own-layer h(t-1), unit j, identical in both halves

    __syncthreads();  // staging + ring init visible (one-time full barrier)

#pragma unroll 1
    for (int t = 0; t < S_LEN + 4; ++t) {
        const int s = t - 2 * w;
        const bool active = (s >= 0) && (s < S_LEN);
        const int wslot = t & 3;
        const int rslot = wslot ^ 2;   // written 2 ticks ago (previous pair)

        // ---- gate matvecs: acc = bias + Whh*h_own + Wih*input ----
        float aA0 = biasA, aA1 = 0.f, aA2 = 0.f, aA3 = 0.f;
        float aB0 = biasB, aB1 = 0.f, aB2 = 0.f, aB3 = 0.f;

        // own h via readlane broadcast (register-only, no LDS)
#pragma unroll
        for (int k4 = 0; k4 < HID / 4; ++k4) {
            const float h0 = bcast(h_own, 4 * k4 + 0);
            const float h1 = bcast(h_own, 4 * k4 + 1);
            const float h2 = bcast(h_own, 4 * k4 + 2);
            const float h3 = bcast(h_own, 4 * k4 + 3);
            aA0 += whA[4 * k4 + 0] * h0;
            aA1 += whA[4 * k4 + 1] * h1;
            aA2 += whA[4 * k4 + 2] * h2;
            aA3 += whA[4 * k4 + 3] * h3;
            aB0 += whB[4 * k4 + 0] * h0;
            aB1 += whB[4 * k4 + 1] * h1;
            aB2 += whB[4 * k4 + 2] * h2;
            aB3 += whB[4 * k4 + 3] * h3;
        }

        if (w == 0) {
            if (active) {   // wave-uniform branch
                const float4 xv = xl4[s];
                const float  x4 = xl1[s];
                aA0 += wxA[0] * xv.x; aB0 += wxB[0] * xv.x;
                aA1 += wxA[1] * xv.y; aB1 += wxB[1] * xv.y;
                aA2 += wxA[2] * xv.z; aB2 += wxB[2] * xv.z;
                aA3 += wxA[3] * xv.w; aB3 += wxB[3] * xv.w;
                aA0 += wxA[4] * x4;   aB0 += wxB[4] * x4;
            }
        } else {
            // input = previous layer's h from ring (broadcast b128 reads;
            // slot written 2 ticks ago, visible via the pair barrier)
            const float4* hin4 =
                reinterpret_cast<const float4*>(&ring[rslot][w - 1][0]);
#pragma unroll
            for (int k4 = 0; k4 < HID / 4; ++k4) {
                float4 hv = hin4[k4];
                aA0 += wiA[4 * k4 + 0] * hv.x;
                aA1 += wiA[4 * k4 + 1] * hv.y;
                aA2 += wiA[4 * k4 + 2] * hv.z;
                aA3 += wiA[4 * k4 + 3] * hv.w;
                aB0 += wiB[4 * k4 + 0] * hv.x;
                aB1 += wiB[4 * k4 + 1] * hv.y;
                aB2 += wiB[4 * k4 + 2] * hv.z;
                aB3 += wiB[4 * k4 + 3] * hv.w;
            }
        }
        const float accA = (aA0 + aA1) + (aA2 + aA3);
        const float accB = (aB0 + aB1) + (aB2 + aB3);

        // ---- half-exchange: all lanes get all 4 gates of unit j ----
        float yf, yi, yo, yg;
        swap_halves(accA, yf, yi);   // low half held i, high half held f
        swap_halves(accB, yo, yg);   // low half held g, high half held o

        const float gi = fast_rcp(1.0f + fast_exp2(-yi));
        const float gf = fast_rcp(1.0f + fast_exp2(-yf));
        const float sg = fast_rcp(1.0f + fast_exp2(-yg));
        const float go = fast_rcp(1.0f + fast_exp2(-yo));

        // c_new = gf*c + gi*(2*sg - 1) = gf*c + 2*(gi*sg) - gi
        const float gisg  = gi * sg;
        const float c_new = gf * c + 2.0f * gisg - gi;
        // tanh(c) = 2*sigma(2c) - 1, no fabs/copysign (limits correct)
        const float tc = 2.0f * fast_rcp(1.0f +
                             fast_exp2(-2.0f * LOG2E * c_new)) - 1.0f;
        const float h = go * tc;                // identical in both halves

        if (active) {
            c = c_new;
            h_own = h;                          // stays in registers
            if (w < 2) {
                if (l < 32) ring[wslot][w][j] = h;    // for layer w+1, t+2
            } else {
                // collapsed MLP: y = relu(v.h + cbias), VALU-only DPP reduce
                const float tot = wave_sum64_dpp(h * v_j);
                const float y = fmaxf(tot + cbias, 0.0f);
                if (l == 63)
                    out[(size_t)s * BATCH + b] = y;   // streamed, unwaited
            }
        }
        if (t & 1) tick_barrier();   // ONE barrier per tick-pair
    }
}

extern "C" void kernel_launch(void* const* d_in, const int* in_sizes, int n_in,
                              void* d_out, int out_size, void* d_ws, size_t ws_size,
                              hipStream_t stream)
{
    const float* x    = (const float*)d_in[0];
    const float* Wih0 = (const float*)d_in[1];
    const float* Whh0 = (const float*)d_in[2];
    const float* bih0 = (const float*)d_in[3];
    const float* bhh0 = (const float*)d_in[4];
    const float* Wih1 = (const float*)d_in[5];
    const float* Whh1 = (const float*)d_in[6];
    const float* bih1 = (const float*)d_in[7];
    const float* bhh1 = (const float*)d_in[8];
    const float* Wih2 = (const float*)d_in[9];
    const float* Whh2 = (const float*)d_in[10];
    const float* bih2 = (const float*)d_in[11];
    const float* bhh2 = (const float*)d_in[12];
    const float* w1   = (const float*)d_in[13];
    const float* b1   = (const float*)d_in[14];
    const float* w2   = (const float*)d_in[15];
    const float* b2   = (const float*)d_in[16];
    const float* w3   = (const float*)d_in[17];
    const float* b3   = (const float*)d_in[18];

    lstm3_fused<<<BATCH, 192, 0, stream>>>(x, Wih0, Whh0, bih0, bhh0,
                                           Wih1, Whh1, bih1, bhh1,
                                           Wih2, Whh2, bih2, bhh2,
                                           w1, b1, w2, b2, w3, b3,
                                           (float*)d_out);
}

// Round 17
// 847.848 us; speedup vs baseline: 1.1224x; 1.0296x over previous
//
#include <hip/hip_runtime.h>
#include <math.h>

// Problem constants (reference: S,B,I,H = 1024,512,5,32; G=4H=128)
#define S_LEN 1024
#define BATCH 512
#define HID   32

#define LOG2E 1.44269504088896340736f

__device__ __forceinline__ float fast_rcp(float x) { return __builtin_amdgcn_rcpf(x); }
__device__ __forceinline__ float fast_exp2(float x) { return __builtin_amdgcn_exp2f(x); }

// Barrier WITHOUT vmcnt drain (out stores stream; never waited in-loop).
__device__ __forceinline__ void tick_barrier() {
    asm volatile("s_waitcnt lgkmcnt(0)" ::: "memory");
    __builtin_amdgcn_s_barrier();
    asm volatile("" ::: "memory");   // compiler fence: no LDS op hoisted above
}

// gfx950 v_permlane32_swap_b32 with vdst = vsrc = v:
//   r[0] = value the HIGH half held, r[1] = value the LOW half held
typedef unsigned int uint2v __attribute__((ext_vector_type(2)));
__device__ __forceinline__ void swap_halves(float v, float& hiAll, float& loAll) {
    uint2v r = __builtin_amdgcn_permlane32_swap(__float_as_uint(v),
                                                __float_as_uint(v),
                                                false, false);
    hiAll = __uint_as_float(r[0]);
    loAll = __uint_as_float(r[1]);
}

// Broadcast lane k's value (k constant after unroll) -> SGPR operand.
__device__ __forceinline__ float bcast(float v, int k) {
    return __int_as_float(__builtin_amdgcn_readlane(__float_as_int(v), k));
}

// Full-wave (64-lane) sum via DPP — VALU-only (round-11: -118 us vs shfl).
// Valid total lands in LANE 63.
__device__ __forceinline__ float wave_sum64_dpp(float v) {
    float s = v;
    s += __int_as_float(__builtin_amdgcn_update_dpp(
             0, __float_as_int(s), 0x111, 0xf, 0xf, true));   // row_shr:1
    s += __int_as_float(__builtin_amdgcn_update_dpp(
             0, __float_as_int(s), 0x112, 0xf, 0xf, true));   // row_shr:2
    s += __int_as_float(__builtin_amdgcn_update_dpp(
             0, __float_as_int(s), 0x114, 0xf, 0xf, true));   // row_shr:4
    s += __int_as_float(__builtin_amdgcn_update_dpp(
             0, __float_as_int(s), 0x118, 0xf, 0xf, true));   // row_shr:8
    s += __int_as_float(__builtin_amdgcn_update_dpp(
             0, __float_as_int(s), 0x142, 0xa, 0xf, true));   // row_bcast:15
    s += __int_as_float(__builtin_amdgcn_update_dpp(
             0, __float_as_int(s), 0x143, 0xc, 0xf, true));   // row_bcast:31
    return s;
}

// Load one 32-float weight row into registers, pre-scaled.
#define LOADROW(dst, base, row, sc)                                            \
    {                                                                          \
        const float4* W_ = reinterpret_cast<const float4*>((base) +            \
                                                    (size_t)(row) * HID);      \
        _Pragma("unroll")                                                      \
        for (int k4 = 0; k4 < 8; ++k4) {                                       \
            float4 v_ = W_[k4];                                                \
            dst[4 * k4 + 0] = v_.x * (sc);                                     \
            dst[4 * k4 + 1] = v_.y * (sc);                                     \
            dst[4 * k4 + 2] = v_.z * (sc);                                     \
            dst[4 * k4 + 3] = v_.w * (sc);                                     \
        }                                                                      \
    }

// Fused 3-layer LSTM + collapsed MLP head — round-11 configuration, byte-exact
// restore (best verified: 848 us total / 820 us kernel). 16 rounds of A/Bs
// bracket this as the floor of the design space:
//   - structure: 3 waves/block (wave w = layer w), 512 blocks = 2 blocks/CU
//     co-resident (cross-block overlap hides per-wave stalls; alternatives —
//     6-wave split, 1-wave sequential, BPB=2, async counters — all regressed)
//   - lag-2 pipeline: wave w at s = t-2w; ring depth 4 (writer t&3, reader
//     (t&3)^2); ONE lgkmcnt-only barrier per tick-pair (no vmcnt drain: out
//     stores stream)
//   - own-layer h stays in registers (readlane broadcast); only the
//     layer->layer+1 hand-off goes through LDS
//   - MLP collapsed to y = relu(v.h2 + cbias), v = 0.5*W1^T(W2^T w3);
//     VALU-only DPP reduce (x0.5 compensates replicated-halves double-count)
//   - weights pre-scaled by log2e (g rows by 2*log2e): uniform activation
//     sigma(y)=rcp(1+exp2(-y)); tanh(g)=2*sigma(2g)-1
//   - unroll-1 + waves_per_eu(2): keep combined VGPR+AGPR under the 256
//     cliff (round-9: crossing it serializes the 2 blocks/CU -> 1.74x)
// Remaining stall (~50%) is dependency latency of the serial recurrence at
// 1.5 waves/SIMD — not memory (1.6% HBM), not issue throughput (VALU 48%).
__global__ __launch_bounds__(192)
__attribute__((amdgpu_waves_per_eu(2)))
void lstm3_fused(const float* __restrict__ x,
                 const float* __restrict__ Wih0, const float* __restrict__ Whh0,
                 const float* __restrict__ bih0, const float* __restrict__ bhh0,
                 const float* __restrict__ Wih1, const float* __restrict__ Whh1,
                 const float* __restrict__ bih1, const float* __restrict__ bhh1,
                 const float* __restrict__ Wih2, const float* __restrict__ Whh2,
                 const float* __restrict__ bih2, const float* __restrict__ bhh2,
                 const float* __restrict__ w1, const float* __restrict__ b1,
                 const float* __restrict__ w2, const float* __restrict__ b2,
                 const float* __restrict__ w3, const float* __restrict__ b3,
                 float* __restrict__ out)
{
    const int b = blockIdx.x;
    const int w = threadIdx.x >> 6;   // wave id == layer id, 0..2
    const int l = threadIdx.x & 63;
    const int j = l & 31;
    const int gA = l;
    const int gB = l + 64;
    const float sA = LOG2E;
    const float sB = (l < 32) ? (2.0f * LOG2E) : LOG2E;  // g rows get 2*log2e

    // x slice: xl4[s] = x[s][b][0..3], xl1[s] = x[s][b][4]
    __shared__ float4 xl4[S_LEN];     // 16 KB
    __shared__ float  xl1[S_LEN];     //  4 KB
    // ring[slot][src_wave][unit]; slot = tick & 3 (lag-2, depth-4)
    __shared__ float ring[4][2][HID];

    for (int i = threadIdx.x; i < 4 * 2 * HID; i += 192)
        (&ring[0][0][0])[i] = 0.0f;
    {
        float* xf = reinterpret_cast<float*>(xl4);
        for (int idx = threadIdx.x; idx < S_LEN * 5; idx += 192) {
            const int s = idx / 5;
            const int c = idx - 5 * s;
            const float v = x[(size_t)s * (BATCH * 5) + b * 5 + c];
            if (c < 4) xf[s * 4 + c] = v;
            else       xl1[s] = v;
        }
    }

    const float* Wih = (w == 0) ? Wih0 : (w == 1) ? Wih1 : Wih2;
    const float* Whh = (w == 0) ? Whh0 : (w == 1) ? Whh1 : Whh2;
    const float* bih = (w == 0) ? bih0 : (w == 1) ? bih1 : bih2;
    const float* bhh = (w == 0) ? bhh0 : (w == 1) ? bhh1 : bhh2;

    // Recurrent weight rows in registers (all waves), pre-scaled
    float whA[HID], whB[HID];
    LOADROW(whA, Whh, gA, sA);
    LOADROW(whB, Whh, gB, sB);
    // Input weight rows: wave 0 has KIN=5, waves 1/2 have KIN=32.
    float wiA[HID], wiB[HID];
    float wxA[5], wxB[5];
    if (w == 0) {
#pragma unroll
        for (int k = 0; k < 5; ++k) {
            wxA[k] = Wih[gA * 5 + k] * sA;
            wxB[k] = Wih[gB * 5 + k] * sB;
        }
    } else {
        LOADROW(wiA, Wih, gA, sA);
        LOADROW(wiB, Wih, gB, sB);
    }
    const float biasA = (bih[gA] + bhh[gA]) * sA;
    const float biasB = (bih[gB] + bhh[gB]) * sB;

    // Collapsed MLP: v_j (x0.5 for the 64-lane DPP sum) and cbias (wave 2)
    float v_j = 0.0f, cbias = 0.0f;
    if (w == 2) {
        float uacc[HID];
#pragma unroll
        for (int k = 0; k < HID; ++k) uacc[k] = 0.0f;
        for (int r = 0; r < HID; ++r) {         // u = w3^T W2 (uniform loads)
            const float w3r = w3[r];
#pragma unroll
            for (int k = 0; k < HID; ++k)
                uacc[k] += w3r * w2[r * HID + k];
        }
#pragma unroll
        for (int k = 0; k < HID; ++k) {
            v_j   += uacc[k] * w1[k * HID + j];
            cbias += uacc[k] * b1[k];
        }
        for (int r = 0; r < HID; ++r) cbias += w3[r] * b2[r];
        cbias += b3[0];
        v_j *= 0.5f;    // halves replicated -> 64-lane sum double-counts
    }

    float c = 0.0f;
    float h_own = 0.0f;   // own-layer h(t-1), unit j, identical in both halves

    __syncthreads();  // staging + ring init visible (one-time full barrier)

#pragma unroll 1
    for (int t = 0; t < S_LEN + 4; ++t) {
        const int s = t - 2 * w;
        const bool active = (s >= 0) && (s < S_LEN);
        const int wslot = t & 3;
        const int rslot = wslot ^ 2;   // written 2 ticks ago (previous pair)

        // ---- gate matvecs: acc = bias + Whh*h_own + Wih*input ----
        float aA0 = biasA, aA1 = 0.f, aA2 = 0.f, aA3 = 0.f;
        float aB0 = biasB, aB1 = 0.f, aB2 = 0.f, aB3 = 0.f;

        // own h via readlane broadcast (register-only, no LDS)
#pragma unroll
        for (int k4 = 0; k4 < HID / 4; ++k4) {
            const float h0 = bcast(h_own, 4 * k4 + 0);
            const float h1 = bcast(h_own, 4 * k4 + 1);
            const float h2 = bcast(h_own, 4 * k4 + 2);
            const float h3 = bcast(h_own, 4 * k4 + 3);
            aA0 += whA[4 * k4 + 0] * h0;
            aA1 += whA[4 * k4 + 1] * h1;
            aA2 += whA[4 * k4 + 2] * h2;
            aA3 += whA[4 * k4 + 3] * h3;
            aB0 += whB[4 * k4 + 0] * h0;
            aB1 += whB[4 * k4 + 1] * h1;
            aB2 += whB[4 * k4 + 2] * h2;
            aB3 += whB[4 * k4 + 3] * h3;
        }

        if (w == 0) {
            if (active) {   // wave-uniform branch
                const float4 xv = xl4[s];
                const float  x4 = xl1[s];
                aA0 += wxA[0] * xv.x; aB0 += wxB[0] * xv.x;
                aA1 += wxA[1] * xv.y; aB1 += wxB[1] * xv.y;
                aA2 += wxA[2] * xv.z; aB2 += wxB[2] * xv.z;
                aA3 += wxA[3] * xv.w; aB3 += wxB[3] * xv.w;
                aA0 += wxA[4] * x4;   aB0 += wxB[4] * x4;
            }
        } else {
            // input = previous layer's h from ring (broadcast b128 reads;
            // slot written 2 ticks ago, visible via the pair barrier)
            const float4* hin4 =
                reinterpret_cast<const float4*>(&ring[rslot][w - 1][0]);
#pragma unroll
            for (int k4 = 0; k4 < HID / 4; ++k4) {
                float4 hv = hin4[k4];
                aA0 += wiA[4 * k4 + 0] * hv.x;
                aA1 += wiA[4 * k4 + 1] * hv.y;
                aA2 += wiA[4 * k4 + 2] * hv.z;
                aA3 += wiA[4 * k4 + 3] * hv.w;
                aB0 += wiB[4 * k4 + 0] * hv.x;
                aB1 += wiB[4 * k4 + 1] * hv.y;
                aB2 += wiB[4 * k4 + 2] * hv.z;
                aB3 += wiB[4 * k4 + 3] * hv.w;
            }
        }
        const float accA = (aA0 + aA1) + (aA2 + aA3);
        const float accB = (aB0 + aB1) + (aB2 + aB3);

        // ---- half-exchange: all lanes get all 4 gates of unit j ----
        float yf, yi, yo, yg;
        swap_halves(accA, yf, yi);   // low half held i, high half held f
        swap_halves(accB, yo, yg);   // low half held g, high half held o

        const float gi = fast_rcp(1.0f + fast_exp2(-yi));
        const float gf = fast_rcp(1.0f + fast_exp2(-yf));
        const float sg = fast_rcp(1.0f + fast_exp2(-yg));
        const float go = fast_rcp(1.0f + fast_exp2(-yo));
        const float gg = 2.0f * sg - 1.0f;      // tanh(g) = 2*sigma(2g) - 1

        const float c_new = gf * c + gi * gg;
        const float e  = fast_exp2(-2.0f * LOG2E * fabsf(c_new));
        const float tc = copysignf((1.0f - e) * fast_rcp(1.0f + e), c_new);
        const float h = go * tc;                // identical in both halves

        if (active) {
            c = c_new;
            h_own = h;                          // stays in registers
            if (w < 2) {
                if (l < 32) ring[wslot][w][j] = h;    // for layer w+1, t+2
            } else {
                // collapsed MLP: y = relu(v.h + cbias), VALU-only DPP reduce
                const float tot = wave_sum64_dpp(h * v_j);
                const float y = fmaxf(tot + cbias, 0.0f);
                if (l == 63)
                    out[(size_t)s * BATCH + b] = y;   // streamed, unwaited
            }
        }
        if (t & 1) tick_barrier();   // ONE barrier per tick-pair
    }
}

extern "C" void kernel_launch(void* const* d_in, const int* in_sizes, int n_in,
                              void* d_out, int out_size, void* d_ws, size_t ws_size,
                              hipStream_t stream)
{
    const float* x    = (const float*)d_in[0];
    const float* Wih0 = (const float*)d_in[1];
    const float* Whh0 = (const float*)d_in[2];
    const float* bih0 = (const float*)d_in[3];
    const float* bhh0 = (const float*)d_in[4];
    const float* Wih1 = (const float*)d_in[5];
    const float* Whh1 = (const float*)d_in[6];
    const float* bih1 = (const float*)d_in[7];
    const float* bhh1 = (const float*)d_in[8];
    const float* Wih2 = (const float*)d_in[9];
    const float* Whh2 = (const float*)d_in[10];
    const float* bih2 = (const float*)d_in[11];
    const float* bhh2 = (const float*)d_in[12];
    const float* w1   = (const float*)d_in[13];
    const float* b1   = (const float*)d_in[14];
    const float* w2   = (const float*)d_in[15];
    const float* b2   = (const float*)d_in[16];
    const float* w3   = (const float*)d_in[17];
    const float* b3   = (const float*)d_in[18];

    lstm3_fused<<<BATCH, 192, 0, stream>>>(x, Wih0, Whh0, bih0, bhh0,
                                           Wih1, Whh1, bih1, bhh1,
                                           Wih2, Whh2, bih2, bhh2,
                                           w1, b1, w2, b2, w3, b3,
                                           (float*)d_out);
}